// Round 1
// 101.426 us; speedup vs baseline: 1.0752x; 1.0752x over previous
//
#include <hip/hip_runtime.h>
#include <math.h>

// Problem constants (from reference)
constexpr int B_  = 4;
constexpr int NQ_ = 2048;
constexpr int NK_ = 2048;
constexpr int C_  = 4;
constexpr int OUT_ = 64;
constexpr int H_  = 16;
constexpr float WINDOW_ = 0.25f;

constexpr int   TAB_   = 4096;                 // value-table cells over [0, WINDOW)
constexpr float SCALE_ = TAB_ / WINDOW_;       // 16384
constexpr int   QW_    = 4;                    // queries per block (1 per wave)
constexpr int   SLOT_  = 1024;                 // padded keys per (batch,chan)
constexpr int   NBIN_  = 64;                   // position bins over [0,1)
constexpr float SENT_  = 4e9f;                 // sentinel position (out of window)

// d_ws layout
constexpr size_t OFF_TAB  = 0;                         // 4096 float = 16 KB
constexpr size_t OFF_SORT = 16384;                     // 16 slots * 1024 float2 = 128 KB
constexpr size_t OFF_BINS = 16384 + 16 * SLOT_ * 8;    // 16 slots * 65 int

// ---------------------------------------------------------------------------
// Preprocess (32 blocks):
//  blocks 0..15 : tabulate |MLP(d)| at each cell CENTER as a single fp32.
//                 Const-per-cell approx: err <= |f'|*h/2 ~ 1.5e-4 (<< 1.09e-2
//                 output threshold). Single-value table => ds_read_b32 gather
//                 in the main loop (2-way bank aliasing = free).
//  blocks 16..31: counting sort of one (batch,chan)'s keys into 64 position
//                 bins (order within bin irrelevant under sum-reduction);
//                 exclusive prefix = CDF for window skip; sentinel padded.
//                 NBIN=64 keeps per-side CDF slop to ~4 keys avg.
// ---------------------------------------------------------------------------
__global__ __launch_bounds__(256) void preprocess(
    const float* __restrict__ key_pos,
    const float* __restrict__ values,
    const int*   __restrict__ key_chan,
    const float* __restrict__ w0, const float* __restrict__ b0,
    const float* __restrict__ w1, const float* __restrict__ b1,
    const float* __restrict__ w2, const float* __restrict__ b2,
    const float* __restrict__ w3, const float* __restrict__ b3,
    float* __restrict__ tab,
    float2* __restrict__ sorted,
    int*    __restrict__ bins)
{
    const int tid = threadIdx.x;

    if (blockIdx.x < 16) {
        // ---- table build: |f| at cell center ----
        const int i = blockIdx.x * 256 + tid;
        const float x = ((float)i + 0.5f) * (1.0f / SCALE_);
        float h[H_], g[H_];
        #pragma unroll
        for (int j = 0; j < H_; ++j)
            h[j] = fmaxf(fmaf(x, w0[j], b0[j]), 0.f);
        #pragma unroll
        for (int j = 0; j < H_; ++j) {
            float a = b1[j];
            #pragma unroll
            for (int k = 0; k < H_; ++k) a = fmaf(w1[j * H_ + k], h[k], a);
            g[j] = fmaxf(a, 0.f);
        }
        #pragma unroll
        for (int j = 0; j < H_; ++j) {
            float a = b2[j];
            #pragma unroll
            for (int k = 0; k < H_; ++k) a = fmaf(w2[j * H_ + k], g[k], a);
            h[j] = fmaxf(a, 0.f);
        }
        float a = b3[0];
        #pragma unroll
        for (int k = 0; k < H_; ++k) a = fmaf(w3[k], h[k], a);
        tab[i] = fabsf(a);
        return;
    }

    // ---- counting sort for one (batch,chan) ----
    const int slot = blockIdx.x - 16;     // 0..15
    const int b    = slot >> 2;
    const int c    = slot & 3;

    __shared__ int   hist[NBIN_ + 1];
    __shared__ int   ofs [NBIN_];
    __shared__ float lpos[SLOT_];
    __shared__ float lval[SLOT_];

    if (tid <= NBIN_) hist[tid] = 0;
    __syncthreads();

    const float* kp = key_pos  + b * NK_;
    const float* vv = values   + b * NK_;
    const int*   cc = key_chan + b * NK_;

    for (int i = tid; i < NK_; i += 256) {
        if (cc[i] == c) {
            const int bin = min((int)(kp[i] * (float)NBIN_), NBIN_ - 1);
            atomicAdd(&hist[bin], 1);
        }
    }
    __syncthreads();

    if (tid == 0) {
        int run = 0;
        #pragma unroll
        for (int t = 0; t < NBIN_; ++t) {
            const int h = hist[t];
            hist[t] = run; ofs[t] = run; run += h;
        }
        hist[NBIN_] = run;
    }
    __syncthreads();

    const int cnt = hist[NBIN_];          // ~512 << SLOT_
    if (tid <= NBIN_) bins[slot * (NBIN_ + 1) + tid] = hist[tid];

    for (int i = tid; i < NK_; i += 256) {
        if (cc[i] == c) {
            const float p   = kp[i];
            const int   bin = min((int)(p * (float)NBIN_), NBIN_ - 1);
            const int   idx = atomicAdd(&ofs[bin], 1);
            lpos[idx] = p; lval[idx] = vv[i];
        }
    }
    __syncthreads();

    for (int i = tid; i < SLOT_; i += 256)
        sorted[slot * SLOT_ + i] =
            (i < cnt) ? make_float2(lpos[i], lval[i]) : make_float2(SENT_, 0.f);
}

// ---------------------------------------------------------------------------
// Main: block = 4 queries of one batch; wave = ONE query. 2048 blocks ->
// target 8 blocks/CU (8 waves/SIMD TLP; LDS 16KB*8=128KB, VGPR<=64 via
// launch_bounds). The 4 channels are processed INTERLEAVED in one round
// loop with a uniform trip count (max over channels) and next-round loads
// prefetched -> 4 independent global->LDS-gather chains per round instead
// of one serial chain; global latency hides under current-round VALU/ds.
// Overshoot rounds read real-but-out-of-window keys or sentinels: the
// strict dd<WINDOW mask kills them exactly (index clamp only guards the
// theoretical OOB case, never triggered at cnt~512).
// ---------------------------------------------------------------------------
__global__ __launch_bounds__(256, 8) void setconv_main(
    const float*  __restrict__ queries,
    const float2* __restrict__ sorted,
    const int*    __restrict__ bins,
    const float*  __restrict__ tab,
    const float*  __restrict__ wd, const float* __restrict__ bd,
    const float*  __restrict__ wr, const float* __restrict__ br,
    float* __restrict__ out)
{
    __shared__ __align__(16) float ltab[TAB_];

    const int tid = threadIdx.x;

    // stage table: 1024 float4s, 4 per thread
    {
        const float4* t4 = (const float4*)tab;
        float4*       l4 = (float4*)ltab;
        #pragma unroll
        for (int i = 0; i < TAB_ / 4 / 256; ++i)
            l4[i * 256 + tid] = t4[i * 256 + tid];
    }
    __syncthreads();

    const int blk  = blockIdx.x;        // 2048 blocks: b = blk>>9, tile = blk&511
    const int b    = blk >> 9;
    const int tile = blk & 511;
    const int wave = tid >> 6;
    const int lane = tid & 63;

    const int   qi   = tile * QW_ + wave;
    const float qpos = queries[b * NQ_ + qi];

    int lo_bin = (int)floorf((qpos - WINDOW_) * (float)NBIN_);
    lo_bin = (lo_bin < 0) ? 0 : ((lo_bin > NBIN_) ? NBIN_ : lo_bin);
    int hi_bin = (int)ceilf((qpos + WINDOW_) * (float)NBIN_);
    hi_bin = (hi_bin < 0) ? 0 : ((hi_bin > NBIN_) ? NBIN_ : hi_bin);

    // per-channel segment start / trip count (uniform rounds = max)
    int k[4];
    const float2* seg[4];
    int rounds = 0;
    #pragma unroll
    for (int c = 0; c < 4; ++c) {
        const int slot = b * 4 + c;
        const int* bs  = bins + slot * (NBIN_ + 1);
        k[c] = bs[lo_bin];
        const int span = bs[hi_bin] - k[c];
        const int rc   = (span + 63) >> 6;
        rounds = (rc > rounds) ? rc : rounds;
        seg[c] = sorted + slot * SLOT_;
    }

    float dens[4] = {0.f, 0.f, 0.f, 0.f};
    float num [4] = {0.f, 0.f, 0.f, 0.f};

    // prefetch round 0
    float2 cur[4];
    #pragma unroll
    for (int c = 0; c < 4; ++c)
        cur[c] = seg[c][min(k[c], SLOT_ - 64) + lane];

    for (int r = 0; r < rounds; ++r) {
        float2 nxt[4];
        #pragma unroll
        for (int c = 0; c < 4; ++c)
            nxt[c] = seg[c][min(k[c] + 64, SLOT_ - 64) + lane];

        #pragma unroll
        for (int c = 0; c < 4; ++c) {
            const float dd = fabsf(cur[c].x - qpos);
            const float t  = fminf(dd * SCALE_, (float)(TAB_ - 1));
            const float tv = ltab[(int)t];       // ds_read_b32 gather
            const float w  = (dd < WINDOW_) ? tv : 0.f;
            dens[c] += w;
            num [c]  = fmaf(w, cur[c].y, num[c]);
        }

        #pragma unroll
        for (int c = 0; c < 4; ++c) { cur[c] = nxt[c]; k[c] += 64; }
    }

    // 64-lane butterfly: every lane ends with the full sums
    #pragma unroll
    for (int off = 32; off >= 1; off >>= 1) {
        #pragma unroll
        for (int c = 0; c < 4; ++c) {
            dens[c] += __shfl_xor(dens[c], off, 64);
            num [c] += __shfl_xor(num [c], off, 64);
        }
    }

    // fused epilogue, redundantly per lane; lane == output channel.
    // (epilogue-only loads keep the main-loop live range small.)
    const float wd0 = wd[0];
    const float bd0 = bd[0];
    float wrow[8];
    #pragma unroll
    for (int j = 0; j < 8; ++j) wrow[j] = wr[lane * 8 + j];
    float acc = br[lane];

    #pragma unroll
    for (int c = 0; c < 4; ++c) {
        const float tgt = num[c] / (dens[c] + 1e-5f);
        const float x   = (dens[c] * 0.1f - 1.0f) * wd0 + bd0;
        const float df  = 1.0f / (1.0f + expf(-x));
        acc = fmaf(wrow[2 * c],     tgt, acc);
        acc = fmaf(wrow[2 * c + 1], df,  acc);
    }
    out[(b * NQ_ + qi) * OUT_ + lane] = acc;
}

extern "C" void kernel_launch(void* const* d_in, const int* in_sizes, int n_in,
                              void* d_out, int out_size, void* d_ws, size_t ws_size,
                              hipStream_t stream) {
    (void)in_sizes; (void)n_in; (void)out_size; (void)ws_size;

    char* ws = (char*)d_ws;
    float*  tab    = (float*) (ws + OFF_TAB);
    float2* sorted = (float2*)(ws + OFF_SORT);
    int*    bins   = (int*)   (ws + OFF_BINS);

    preprocess<<<dim3(32), dim3(256), 0, stream>>>(
        (const float*)d_in[0],  // key_pos
        (const float*)d_in[2],  // values
        (const int*)  d_in[3],  // key_chan
        (const float*)d_in[4],  (const float*)d_in[5],   // w0 b0
        (const float*)d_in[6],  (const float*)d_in[7],   // w1 b1
        (const float*)d_in[8],  (const float*)d_in[9],   // w2 b2
        (const float*)d_in[10], (const float*)d_in[11],  // w3 b3
        tab, sorted, bins);

    setconv_main<<<dim3(B_ * (NQ_ / QW_)), dim3(256), 0, stream>>>(
        (const float*)d_in[1],  // queries
        sorted, bins, tab,
        (const float*)d_in[12], (const float*)d_in[13],  // wd bd
        (const float*)d_in[14], (const float*)d_in[15],  // wr br
        (float*)d_out);
}

// Round 2
// 99.149 us; speedup vs baseline: 1.0999x; 1.0230x over previous
//
#include <hip/hip_runtime.h>
#include <math.h>

// Problem constants (from reference)
constexpr int B_  = 4;
constexpr int NQ_ = 2048;
constexpr int NK_ = 2048;
constexpr int C_  = 4;
constexpr int OUT_ = 64;
constexpr int H_  = 16;
constexpr float WINDOW_ = 0.25f;

constexpr int   TAB_   = 4096;                 // value-table cells over [0, WINDOW)
constexpr float SCALE_ = TAB_ / WINDOW_;       // 16384
constexpr int   QW_    = 4;                    // queries per block (1 per wave)
constexpr int   SLOT_  = 1024;                 // padded keys per (batch,chan)
constexpr int   NBIN_  = 64;                   // position bins over [0,1)
constexpr float SENT_  = 4e9f;                 // sentinel position (out of window)

// d_ws layout
constexpr size_t OFF_TAB  = 0;                         // 4096 float = 16 KB
constexpr size_t OFF_SORT = 16384;                     // 16 slots * 1024 float2 = 128 KB
constexpr size_t OFF_BINS = 16384 + 16 * SLOT_ * 8;    // 16 slots * 65 int

// ---------------------------------------------------------------------------
// Preprocess (32 blocks):
//  blocks 0..15 : tabulate |MLP(d)| at each cell CENTER as a single fp32.
//                 Const-per-cell approx: err <= |f'|*h/2 ~ 1.5e-4 (<< 1.09e-2
//                 output threshold).
//  blocks 16..31: counting sort of one (batch,chan)'s keys into 64 position
//                 bins. Single register-resident read pass (NK = 8*256
//                 exactly): chan/pos/val live in regs across the histogram
//                 and scatter phases — halves global-load latency chains.
// ---------------------------------------------------------------------------
__global__ __launch_bounds__(256) void preprocess(
    const float* __restrict__ key_pos,
    const float* __restrict__ values,
    const int*   __restrict__ key_chan,
    const float* __restrict__ w0, const float* __restrict__ b0,
    const float* __restrict__ w1, const float* __restrict__ b1,
    const float* __restrict__ w2, const float* __restrict__ b2,
    const float* __restrict__ w3, const float* __restrict__ b3,
    float* __restrict__ tab,
    float2* __restrict__ sorted,
    int*    __restrict__ bins)
{
    const int tid = threadIdx.x;

    if (blockIdx.x < 16) {
        // ---- table build: |f| at cell center ----
        const int i = blockIdx.x * 256 + tid;
        const float x = ((float)i + 0.5f) * (1.0f / SCALE_);
        float h[H_], g[H_];
        #pragma unroll
        for (int j = 0; j < H_; ++j)
            h[j] = fmaxf(fmaf(x, w0[j], b0[j]), 0.f);
        #pragma unroll
        for (int j = 0; j < H_; ++j) {
            float a = b1[j];
            #pragma unroll
            for (int k = 0; k < H_; ++k) a = fmaf(w1[j * H_ + k], h[k], a);
            g[j] = fmaxf(a, 0.f);
        }
        #pragma unroll
        for (int j = 0; j < H_; ++j) {
            float a = b2[j];
            #pragma unroll
            for (int k = 0; k < H_; ++k) a = fmaf(w2[j * H_ + k], g[k], a);
            h[j] = fmaxf(a, 0.f);
        }
        float a = b3[0];
        #pragma unroll
        for (int k = 0; k < H_; ++k) a = fmaf(w3[k], h[k], a);
        tab[i] = fabsf(a);
        return;
    }

    // ---- counting sort for one (batch,chan), single global read pass ----
    const int slot = blockIdx.x - 16;     // 0..15
    const int b    = slot >> 2;
    const int c    = slot & 3;

    __shared__ int   hist[NBIN_ + 1];
    __shared__ int   ofs [NBIN_];
    __shared__ float lpos[SLOT_];
    __shared__ float lval[SLOT_];

    if (tid <= NBIN_) hist[tid] = 0;

    const float* kp = key_pos  + b * NK_;
    const float* vv = values   + b * NK_;
    const int*   cc = key_chan + b * NK_;

    constexpr int EPT = NK_ / 256;        // 8 elements per thread
    int   ch[EPT]; float p[EPT]; float v[EPT]; int bn[EPT];
    #pragma unroll
    for (int t = 0; t < EPT; ++t) {
        const int i = t * 256 + tid;
        ch[t] = cc[i]; p[t] = kp[i]; v[t] = vv[i];
        bn[t] = min((int)(p[t] * (float)NBIN_), NBIN_ - 1);
    }
    __syncthreads();                      // hist zeroed

    #pragma unroll
    for (int t = 0; t < EPT; ++t)
        if (ch[t] == c) atomicAdd(&hist[bn[t]], 1);
    __syncthreads();

    if (tid == 0) {
        int run = 0;
        #pragma unroll
        for (int t = 0; t < NBIN_; ++t) {
            const int h = hist[t];
            hist[t] = run; ofs[t] = run; run += h;
        }
        hist[NBIN_] = run;
    }
    __syncthreads();

    const int cnt = hist[NBIN_];          // ~512 << SLOT_
    if (tid <= NBIN_) bins[slot * (NBIN_ + 1) + tid] = hist[tid];

    #pragma unroll
    for (int t = 0; t < EPT; ++t) {
        if (ch[t] == c) {
            const int idx = atomicAdd(&ofs[bn[t]], 1);
            lpos[idx] = p[t]; lval[idx] = v[t];
        }
    }
    __syncthreads();

    for (int i = tid; i < SLOT_; i += 256)
        sorted[slot * SLOT_ + i] =
            (i < cnt) ? make_float2(lpos[i], lval[i]) : make_float2(SENT_, 0.f);
}

// ---------------------------------------------------------------------------
// Main: block = 4 queries of one batch; wave = ONE query; within the wave,
// 16 lanes per channel (4 channels side-by-side). Loop throughput is the
// same 64 key-visits/round as the channel-interleaved version, but fixed
// per-wave overhead shrinks: epilogue is 14 shuffles instead of 48
// (4 intra-group butterfly levels x 2 values + 6 cross-group exchanges),
// prologue is 2 bins loads/lane instead of 8, and k/seg/cur are scalars
// (lower VGPR live range). Next-round load prefetched; the strict
// dd<WINDOW mask exactly kills bin-boundary slop, overshoot and sentinels.
// ---------------------------------------------------------------------------
__global__ __launch_bounds__(256, 8) void setconv_main(
    const float*  __restrict__ queries,
    const float2* __restrict__ sorted,
    const int*    __restrict__ bins,
    const float*  __restrict__ tab,
    const float*  __restrict__ wd, const float* __restrict__ bd,
    const float*  __restrict__ wr, const float* __restrict__ br,
    float* __restrict__ out)
{
    __shared__ __align__(16) float ltab[TAB_];

    const int tid = threadIdx.x;

    // stage table: 1024 float4s, 4 per thread
    {
        const float4* t4 = (const float4*)tab;
        float4*       l4 = (float4*)ltab;
        #pragma unroll
        for (int i = 0; i < TAB_ / 4 / 256; ++i)
            l4[i * 256 + tid] = t4[i * 256 + tid];
    }
    __syncthreads();

    const int blk  = blockIdx.x;        // 2048 blocks: b = blk>>9, tile = blk&511
    const int b    = blk >> 9;
    const int tile = blk & 511;
    const int wave = tid >> 6;
    const int lane = tid & 63;
    const int g    = lane >> 4;         // my channel
    const int l16  = lane & 15;

    const int   qi   = tile * QW_ + wave;
    const float qpos = queries[b * NQ_ + qi];

    int lo_bin = (int)floorf((qpos - WINDOW_) * (float)NBIN_);
    lo_bin = (lo_bin < 0) ? 0 : ((lo_bin > NBIN_) ? NBIN_ : lo_bin);
    int hi_bin = (int)ceilf((qpos + WINDOW_) * (float)NBIN_);
    hi_bin = (hi_bin < 0) ? 0 : ((hi_bin > NBIN_) ? NBIN_ : hi_bin);

    // my channel's segment window
    const int slot = b * 4 + g;
    const int* bs  = bins + slot * (NBIN_ + 1);
    const int k0   = bs[lo_bin];
    const int span = bs[hi_bin] - k0;
    const float2* seg = sorted + slot * SLOT_;

    // wave-uniform trip count = max over the 4 channel groups
    int rounds = (span + 15) >> 4;
    rounds = max(rounds, __shfl_xor(rounds, 16, 64));
    rounds = max(rounds, __shfl_xor(rounds, 32, 64));

    float d = 0.f, n = 0.f;

    // prefetch round 0 (base clamp: statistically never active at cnt~512,
    // guards the theoretical OOB; masked reads are exactly killed by dd<W)
    float2 cur = seg[min(k0, SLOT_ - 16) + l16];

    for (int r = 0; r < rounds; ++r) {
        const float2 nxt = seg[min(k0 + ((r + 1) << 4), SLOT_ - 16) + l16];

        const float dd = fabsf(cur.x - qpos);
        const float t  = fminf(dd * SCALE_, (float)(TAB_ - 1));
        const float tv = ltab[(int)t];       // ds_read_b32 gather
        const float w  = (dd < WINDOW_) ? tv : 0.f;
        d += w;
        n  = fmaf(w, cur.y, n);

        cur = nxt;
    }

    // intra-group butterfly (16 lanes share a channel): 4 levels x 2 values
    #pragma unroll
    for (int off = 8; off >= 1; off >>= 1) {
        d += __shfl_xor(d, off, 64);
        n += __shfl_xor(n, off, 64);
    }
    // cross-group exchange: Dv[m]/Nv[m] hold channel (g ^ m)
    float Dv[4], Nv[4];
    Dv[0] = d;                      Nv[0] = n;
    Dv[1] = __shfl_xor(d, 16, 64);  Nv[1] = __shfl_xor(n, 16, 64);
    Dv[2] = __shfl_xor(d, 32, 64);  Nv[2] = __shfl_xor(n, 32, 64);
    Dv[3] = __shfl_xor(d, 48, 64);  Nv[3] = __shfl_xor(n, 48, 64);

    // fused epilogue, redundantly per lane; lane == output channel.
    const float wd0 = wd[0];
    const float bd0 = bd[0];
    float acc = br[lane];

    #pragma unroll
    for (int m = 0; m < 4; ++m) {
        const int   c   = g ^ m;
        const float tgt = Nv[m] / (Dv[m] + 1e-5f);
        const float x   = (Dv[m] * 0.1f - 1.0f) * wd0 + bd0;
        const float df  = 1.0f / (1.0f + expf(-x));
        acc = fmaf(wr[lane * 8 + 2 * c],     tgt, acc);
        acc = fmaf(wr[lane * 8 + 2 * c + 1], df,  acc);
    }
    out[(b * NQ_ + qi) * OUT_ + lane] = acc;
}

extern "C" void kernel_launch(void* const* d_in, const int* in_sizes, int n_in,
                              void* d_out, int out_size, void* d_ws, size_t ws_size,
                              hipStream_t stream) {
    (void)in_sizes; (void)n_in; (void)out_size; (void)ws_size;

    char* ws = (char*)d_ws;
    float*  tab    = (float*) (ws + OFF_TAB);
    float2* sorted = (float2*)(ws + OFF_SORT);
    int*    bins   = (int*)   (ws + OFF_BINS);

    preprocess<<<dim3(32), dim3(256), 0, stream>>>(
        (const float*)d_in[0],  // key_pos
        (const float*)d_in[2],  // values
        (const int*)  d_in[3],  // key_chan
        (const float*)d_in[4],  (const float*)d_in[5],   // w0 b0
        (const float*)d_in[6],  (const float*)d_in[7],   // w1 b1
        (const float*)d_in[8],  (const float*)d_in[9],   // w2 b2
        (const float*)d_in[10], (const float*)d_in[11],  // w3 b3
        tab, sorted, bins);

    setconv_main<<<dim3(B_ * (NQ_ / QW_)), dim3(256), 0, stream>>>(
        (const float*)d_in[1],  // queries
        sorted, bins, tab,
        (const float*)d_in[12], (const float*)d_in[13],  // wd bd
        (const float*)d_in[14], (const float*)d_in[15],  // wr br
        (float*)d_out);
}